// Round 18
// baseline (1835.322 us; speedup 1.0000x reference)
//
#include <hip/hip_runtime.h>
#include <math.h>

namespace {

constexpr int kB  = 256;   // batch
constexpr int kT  = 512;   // timesteps
constexpr int kIn = 128;   // layer0 input size
constexpr int kH  = 256;   // hidden
constexpr int kG  = 1024;  // 4*H
constexpr int kNC = 100;   // classes
constexpr int kCT = 64;    // timestep chunk
constexpr int kNCh = kT / kCT;
constexpr int kGdStride = 1280;  // ints per gdone slot (64*16 flags + gall)

typedef __bf16 bf16x8 __attribute__((ext_vector_type(8)));
typedef float f32x4 __attribute__((ext_vector_type(4)));
typedef int i32x4 __attribute__((ext_vector_type(4)));
typedef unsigned short u16;
static_assert(sizeof(bf16x8) == 16, "bf16x8 must be 4 VGPRs");

__device__ __forceinline__ float sigm(float x) {
  return __builtin_amdgcn_rcpf(1.0f + __expf(-x));
}
__device__ __forceinline__ float tanh_f(float x) {
  const float e = __expf(-2.0f * x);
  return (1.0f - e) * __builtin_amdgcn_rcpf(1.0f + e);
}
__device__ __forceinline__ u16 f2bf(float f) {
  return __builtin_bit_cast(u16, (__bf16)f);
}
__device__ __forceinline__ float bf2f(u16 v) {
  return __builtin_bit_cast(float, ((unsigned)v) << 16);
}

// Async global->LDS, 16B/lane. aux 0 = plain (cached); 17 = sc0|sc1 (LLC).
__device__ __forceinline__ void glds16(const void* g, void* l) {
  __builtin_amdgcn_global_load_lds(
      (const __attribute__((address_space(1))) void*)g,
      (__attribute__((address_space(3))) void*)l, 16, 0, 0);
}
__device__ __forceinline__ void glds16_llc(const void* g, void* l) {
  __builtin_amdgcn_global_load_lds(
      (const __attribute__((address_space(1))) void*)g,
      (__attribute__((address_space(3))) void*)l, 16, 0, 17);
}
// Stores written through to LLC (device-visible after vmcnt drain).
__device__ __forceinline__ void st_bf16_llc(u16* p, u16 v) {
  asm volatile("global_store_short %0, %1, off sc0 sc1"
               :: "v"((unsigned long long)(uintptr_t)p), "v"(v) : "memory");
}
__device__ __forceinline__ void st_i32_llc(int* p, int v) {
  asm volatile("global_store_dword %0, %1, off sc0 sc1"
               :: "v"((unsigned long long)(uintptr_t)p), "v"(v) : "memory");
}
__device__ __forceinline__ void st_i4_llc(void* p, i32x4 v) {
  asm volatile("global_store_dwordx4 %0, %1, off sc0 sc1"
               :: "v"((unsigned long long)(uintptr_t)p), "v"(v) : "memory");
}
// Poll 16 ints (64B) at LLC scope; min of the 16. Early-clobber outputs
// (async VMEM returns must not alias the live address inputs).
__device__ __forceinline__ int poll16_min(const int* p) {
  i32x4 a, b, c, d;
  asm volatile(
      "global_load_dwordx4 %0, %4, off sc0 sc1\n\t"
      "global_load_dwordx4 %1, %5, off sc0 sc1\n\t"
      "global_load_dwordx4 %2, %6, off sc0 sc1\n\t"
      "global_load_dwordx4 %3, %7, off sc0 sc1\n\t"
      "s_waitcnt vmcnt(0)"
      : "=&v"(a), "=&v"(b), "=&v"(c), "=&v"(d)
      : "v"((unsigned long long)(uintptr_t)p),
        "v"((unsigned long long)(uintptr_t)(p + 4)),
        "v"((unsigned long long)(uintptr_t)(p + 8)),
        "v"((unsigned long long)(uintptr_t)(p + 12))
      : "memory");
  int m = a.x;
  m = min(m, a.y); m = min(m, a.z); m = min(m, a.w);
  m = min(m, b.x); m = min(m, b.y); m = min(m, b.z); m = min(m, b.w);
  m = min(m, c.x); m = min(m, c.y); m = min(m, c.z); m = min(m, c.w);
  m = min(m, d.x); m = min(m, d.y); m = min(m, d.z); m = min(m, d.w);
  return m;
}
// Issue 4 x 8B LLC-scope loads of P (gate g stride 256 u16), NO waitcnt:
// the next __syncthreads (vmcnt0 drain) completes them; a sched_barrier(0)
// after that barrier stops the compiler hoisting the register-only consume.
__device__ __forceinline__ void pf_issue_llc(const u16* p,
                                             unsigned long long pf[4]) {
  asm volatile(
      "global_load_dwordx2 %0, %4, off sc0 sc1\n\t"
      "global_load_dwordx2 %1, %5, off sc0 sc1\n\t"
      "global_load_dwordx2 %2, %6, off sc0 sc1\n\t"
      "global_load_dwordx2 %3, %7, off sc0 sc1"
      : "=&v"(pf[0]), "=&v"(pf[1]), "=&v"(pf[2]), "=&v"(pf[3])
      : "v"((unsigned long long)(uintptr_t)p),
        "v"((unsigned long long)(uintptr_t)(p + 256)),
        "v"((unsigned long long)(uintptr_t)(p + 512)),
        "v"((unsigned long long)(uintptr_t)(p + 768))
      : "memory");
}

// ---------------------------------------------------------------------------
// Pack W_hh [4H][H] fp32 -> bf16 MFMA B-frags for the recurrence.
__global__ __launch_bounds__(256) void pack_whh_frag(
    const float* __restrict__ whh, u16* __restrict__ wpk) {
  const int idx = blockIdx.x * 256 + threadIdx.x;   // 0..262143
  const int e  = idx & 7;
  const int l  = (idx >> 3) & 63;
  const int kb = (idx >> 9) & 7;
  const int g  = (idx >> 12) & 3;
  const int wv = idx >> 14;
  const int n = (g << 8) | (wv << 4) | (l & 15);
  const int k = (kb << 5) | (((l >> 4) & 3) << 3) | e;
  wpk[idx] = f2bf(whh[n * kH + k]);
}

// Pack W_ih [kG][K] fp32 -> bf16 B-frags for the projection GEMM.
template <int K>
__global__ __launch_bounds__(256) void pack_wih_frag(
    const float* __restrict__ w, u16* __restrict__ wp) {
  constexpr int kbBits = (K == 128) ? 2 : 3;
  const int idx = blockIdx.x * 256 + threadIdx.x;
  const int e  = idx & 7;
  const int l  = (idx >> 3) & 63;
  const int kb = (idx >> 9) & ((K / 32) - 1);
  const int n16 = idx >> (9 + kbBits);
  const int n = (n16 << 4) | (l & 15);
  const int k = (kb << 5) | (((l >> 4) & 3) << 3) | e;
  wp[idx] = f2bf(w[n * K + k]);
}

// x [B][T][128] fp32 -> xbf [T][B][128] bf16 (t-major for the GEMM).
__global__ __launch_bounds__(256) void conv_x(
    const float* __restrict__ x, u16* __restrict__ xbf) {
  const int f4 = blockIdx.x * 256 + threadIdx.x;   // 0..4194303
  const int rowid = f4 >> 5;                       // b*512 + t
  const int c4 = f4 & 31;
  const int b = rowid >> 9, t = rowid & 511;
  const float4 v = reinterpret_cast<const float4*>(x)[f4];
  ushort4 o;
  o.x = f2bf(v.x); o.y = f2bf(v.y); o.z = f2bf(v.z); o.w = f2bf(v.w);
  reinterpret_cast<ushort4*>(xbf)[(t * 256 + b) * 32 + c4] = o;
}

// ---------------------------------------------------------------------------
// MFMA projection GEMM body (round-8 structure). gbid in [0,1024).
// gflag != null: epilogue stores write-through (sc0sc1), then per-tt flag
// gdone[tt][(g<<2)|bq] = 1 and gall counter (gflag[1024]) increment.
template <int K>
__device__ __forceinline__ void gemm_body(
    const u16* __restrict__ A, const u16* __restrict__ Bp,
    const float* __restrict__ b1, const float* __restrict__ b2,
    u16* __restrict__ P2, int gbid, unsigned char* smem, int* gflag) {
  constexpr int NKB = K / 32;
  const int g = gbid & 3, mt = gbid >> 2;
  const int tt = mt >> 2, bq = mt & 3;
  const int tid = threadIdx.x, w = tid >> 6, l = tid & 63;

  u16* albuf = (u16*)smem;                 // [2][4][512]
  u16* bbuf  = (u16*)(smem + 8192);        // [2][16][512]
  u16* sout  = (u16*)smem;                 // [4][16][256] (epilogue reuse)

  const u16* Ab = A + ((size_t)(tt * 256 + bq * 64 + w * 16 + (l & 15))) * K +
                  ((l >> 4) & 3) * 8;
  const u16* Bb = Bp + ((size_t)((g * 16 + w * 4) * NKB) * 64 + l) * 8;

  float bb[4];
#pragma unroll
  for (int j = 0; j < 4; ++j) {
    const int n = g * 256 + (w * 4 + j) * 16 + (l & 15);
    bb[j] = b1[n] + b2[n];
  }

  f32x4 acc[4][4];
#pragma unroll
  for (int mf = 0; mf < 4; ++mf)
#pragma unroll
    for (int nf = 0; nf < 4; ++nf) acc[mf][nf] = f32x4{0.f, 0.f, 0.f, 0.f};

#define STAGE(kb, buf)                                                     \
  {                                                                        \
    glds16(Ab + (kb) * 32, albuf + ((buf) * 4 + w) * 512);                 \
    _Pragma("unroll") for (int j = 0; j < 4; ++j)                          \
        glds16(Bb + ((size_t)(j * NKB + (kb)) * 64) * 8,                   \
               bbuf + ((buf) * 16 + w * 4 + j) * 512);                     \
  }

  STAGE(0, 0);
#pragma unroll
  for (int kb = 0; kb < NKB; ++kb) {
    __syncthreads();
    if (kb + 1 < NKB) STAGE(kb + 1, (kb + 1) & 1);
    const int buf = kb & 1;
    bf16x8 af[4], bf[4];
#pragma unroll
    for (int mf = 0; mf < 4; ++mf)
      af[mf] = *reinterpret_cast<const bf16x8*>(albuf + (buf * 4 + mf) * 512 + l * 8);
#pragma unroll
    for (int nf = 0; nf < 4; ++nf)
      bf[nf] = *reinterpret_cast<const bf16x8*>(bbuf + (buf * 16 + w * 4 + nf) * 512 + l * 8);
#pragma unroll
    for (int mf = 0; mf < 4; ++mf)
#pragma unroll
      for (int nf = 0; nf < 4; ++nf)
        acc[mf][nf] = __builtin_amdgcn_mfma_f32_16x16x32_bf16(
            af[mf], bf[nf], acc[mf][nf], 0, 0, 0);
  }
#undef STAGE

  __syncthreads();
#pragma unroll
  for (int mf = 0; mf < 4; ++mf)
#pragma unroll
    for (int nf = 0; nf < 4; ++nf) {
      ushort4 p;
      p.x = f2bf(acc[mf][nf][0] + bb[nf]);
      p.y = f2bf(acc[mf][nf][1] + bb[nf]);
      p.z = f2bf(acc[mf][nf][2] + bb[nf]);
      p.w = f2bf(acc[mf][nf][3] + bb[nf]);
      *reinterpret_cast<ushort4*>(
          sout + (mf * 16 + w * 4 + nf) * 256 + (l & 15) * 16 + ((l >> 4) & 3) * 4) = p;
    }
  __syncthreads();
#pragma unroll
  for (int i = 0; i < 8; ++i) {
    const int chunk = i * 8 + (tid >> 5);  // 0..63
    const int mf = chunk >> 4, wc = chunk & 15;
    const size_t dst =
        ((((size_t)(bq * 4 + mf) * 64 + tt) * 16 + wc) * 4 + g) * 256 +
        (tid & 31) * 8;
    const i32x4 val =
        *reinterpret_cast<const i32x4*>(sout + (mf * 16 + wc) * 256 + (tid & 31) * 8);
    if (gflag) st_i4_llc(P2 + dst, val);
    else       *reinterpret_cast<i32x4*>(P2 + dst) = val;
  }
  if (gflag) {
    asm volatile("s_waitcnt vmcnt(0)" ::: "memory");
    __syncthreads();  // all threads' P2 stores at LLC
    if (tid == 0) {
      st_i32_llc(gflag + tt * 16 + ((g << 2) | bq), 1);
      __hip_atomic_fetch_add(gflag + 1024, 1, __ATOMIC_RELAXED,
                             __HIP_MEMORY_SCOPE_AGENT);
    }
  }
}

// Standalone GEMM kernel (flat 1024-block grid) for the initial gemm0.
template <int K>
__global__ __launch_bounds__(256, 4) void gemm_flat(
    const u16* __restrict__ A, const u16* __restrict__ Bp,
    const float* __restrict__ b1, const float* __restrict__ b2,
    u16* __restrict__ P2) {
  __shared__ __align__(16) unsigned char smem[40960];
  gemm_body<K>(A, Bp, b1, b2, P2, blockIdx.x, smem, nullptr);
}

// ---------------------------------------------------------------------------
// Fused dispatch:
//   blocks    0..127  : dual-role LSTM recurrence (R11 protocol)
//   blocks  128..1151 : gemm1 (K=kH) producing P2b for rec1 IN THIS dispatch
//                       (input H0 parity buffer completed last dispatch ->
//                        gemm1 never waits -> no deadlock possible)
//   blocks 1152..2175 : gemm0 (K=kIn) for the next chunk (fully independent)
// rec1 gates each step's P-prefetch on gemm1's per-tt flags until the gall
// counter shows all 1024 gemm1 blocks done (then gating cost is zero).
__global__ __launch_bounds__(256, 1) void fused_step(
    const u16* __restrict__ P2_0, const u16* __restrict__ wpk_0,
    float* __restrict__ cs_0, u16* __restrict__ Ho_0,
    u16* __restrict__ hx_0, int* __restrict__ tg_0, int first_0,
    const u16* __restrict__ P2_1, const u16* __restrict__ wpk_1,
    float* __restrict__ cs_1, float* __restrict__ hl_1,
    u16* __restrict__ hx_1, int* __restrict__ tg_1, int first_1,
    int* __restrict__ gd1,
    const u16* __restrict__ A1, u16* __restrict__ P1,
    const u16* __restrict__ B1g, const float* __restrict__ b11,
    const float* __restrict__ b21,
    const u16* __restrict__ Ag, u16* __restrict__ Pg,
    const u16* __restrict__ B0g, const float* __restrict__ b10,
    const float* __restrict__ b20) {
  __shared__ __align__(16) unsigned char smem[40960];

  if (blockIdx.x >= 1152) {
    if (Ag) gemm_body<kIn>(Ag, B0g, b10, b20, Pg, blockIdx.x - 1152, smem,
                           nullptr);
    return;
  }
  if (blockIdx.x >= 128) {
    if (A1) gemm_body<kH>(A1, B1g, b11, b21, P1, blockIdx.x - 128, smem, gd1);
    return;
  }

  // ---------------- recurrence (R11 protocol) ----------------
  const int role = blockIdx.x >> 6;
  const u16* P2  = role ? P2_1 : P2_0;
  if (!P2) return;
  const u16* wpk = role ? wpk_1 : wpk_0;
  float* cstate  = role ? cs_1 : cs_0;
  u16* HoutBf    = role ? nullptr : Ho_0;
  float* hlast   = role ? hl_1 : nullptr;
  u16* hx        = role ? hx_1 : hx_0;
  int* tags      = role ? tg_1 : tg_0;
  int* gdone     = role ? gd1 : nullptr;
  const int first = role ? first_1 : first_0;

  const int bid6 = blockIdx.x & 63;
  const int tid = threadIdx.x;
  const int ug = tid >> 6;            // wave in block (0..3)
  const int l  = tid & 63;
  const int bblk = bid6 & 15;         // batch group (16 rows)
  const int hs   = bid6 >> 4;         // hidden slice (64 units)
  const int R0 = bblk << 4;
  const int wv16 = (hs << 2) | ug;
  const int jj = (wv16 << 4) | (l & 15);
  const int mg = ((l >> 4) & 3) << 2;
  const int rowb = R0 + mg;

  u16 (*albuf)[8][512] = reinterpret_cast<u16 (*)[8][512]>(smem);  // 16KB

  int* tgb = tags + bblk * 1024;      // 64 steps x 16 wave-flags
  u16* hx0 = hx;
  u16* hx1 = hx + (size_t)kB * kH;

  // resident B-frags: 4 gates x 8 kb = 128 VGPRs, pinned
  bf16x8 wr[4][8];
#pragma unroll
  for (int g = 0; g < 4; ++g)
#pragma unroll
    for (int kb = 0; kb < 8; ++kb) {
      wr[g][kb] = *reinterpret_cast<const bf16x8*>(
          wpk + (size_t)(((wv16 * 4 + g) * 8 + kb) * 64 + l) * 8);
      asm volatile("" : "+v"(wr[g][kb]));
    }

  // ---- c state ----
  f32x4 c4;
  float hnew[4];
  if (first) {
#pragma unroll
    for (int r = 0; r < 4; ++r) c4[r] = 0.f;
  } else {
#pragma unroll
    for (int r = 0; r < 4; ++r) c4[r] = cstate[(rowb + r) * kH + jj];
  }

  // ---- gemm1-producer gating (role1 only; no-op once gall==1024) ----
  bool alldone = (gdone == nullptr);
  auto gate = [&](int t) {
    if (alldone) return;
    if (__hip_atomic_load(gdone + 1024, __ATOMIC_RELAXED,
                          __HIP_MEMORY_SCOPE_AGENT) >= 1024) {
      alldone = true;
      return;
    }
    while (poll16_min(gdone + t * 16) < 1) __builtin_amdgcn_s_sleep(1);
  };

  // P2 (bf16) lane base
  const u16* __restrict__ Pb =
      P2 + ((size_t)bblk * 64 * 16 + wv16) * 1024 + ((l & 15) << 4) + mg;
  unsigned long long pfq[4];
  gate(0);
  pf_issue_llc(Pb, pfq);  // drained by first loop-top barrier

  const int gkb = ug << 1;
#define ISSUE_GLDS(buf, bsel)                                               \
  {                                                                         \
    _Pragma("unroll") for (int q = 0; q < 2; ++q) {                         \
      const int kb = gkb + q;                                               \
      glds16_llc((buf) + ((size_t)(R0 + (l & 15))) * 256 + kb * 32 +        \
                     ((l >> 4) & 3) * 8,                                    \
                 &albuf[bsel][kb][0]);                                      \
    }                                                                       \
  }

  ISSUE_GLDS(hx0, 0);

  for (int tt = 0; tt < kCT; ++tt) {
    __syncthreads();  // [A] drains glds + pf issues (vmcnt0) for all waves
    __builtin_amdgcn_sched_barrier(0);  // forbid hoisting pf consumes above

    f32x4 acc[4];
#pragma unroll
    for (int g = 0; g < 4; ++g) {
      const ushort4 u = __builtin_bit_cast(ushort4, pfq[g]);
      acc[g][0] = bf2f(u.x);
      acc[g][1] = bf2f(u.y);
      acc[g][2] = bf2f(u.z);
      acc[g][3] = bf2f(u.w);
    }
    const bool more = (tt + 1 < kCT);
    if (more) {
      gate(tt + 1);
      pf_issue_llc(Pb + (size_t)(tt + 1) * 16384, pfq);
    }

    const u16* ab = &albuf[tt & 1][0][0];
#pragma unroll
    for (int kb = 0; kb < 8; ++kb) {
      const bf16x8 a = *reinterpret_cast<const bf16x8*>(ab + kb * 512 + l * 8);
      acc[0] = __builtin_amdgcn_mfma_f32_16x16x32_bf16(a, wr[0][kb], acc[0], 0, 0, 0);
      acc[1] = __builtin_amdgcn_mfma_f32_16x16x32_bf16(a, wr[1][kb], acc[1], 0, 0, 0);
      acc[2] = __builtin_amdgcn_mfma_f32_16x16x32_bf16(a, wr[2][kb], acc[2], 0, 0, 0);
      acc[3] = __builtin_amdgcn_mfma_f32_16x16x32_bf16(a, wr[3][kb], acc[3], 0, 0, 0);
    }

#pragma unroll
    for (int r = 0; r < 4; ++r) {
      const float ig = sigm(acc[0][r]);
      const float fg = sigm(acc[1][r]);
      const float gg = tanh_f(acc[2][r]);
      const float og = sigm(acc[3][r]);
      const float cc = fg * c4[r] + ig * gg;
      c4[r] = cc;
      hnew[r] = og * tanh_f(cc);
    }

    // publish h slice (sc0sc1 -> LLC)
    u16* hw = ((tt + 1) & 1) ? hx1 : hx0;
#pragma unroll
    for (int r = 0; r < 4; ++r)
      st_bf16_llc(hw + ((size_t)(rowb + r) << 8) + jj, f2bf(hnew[r]));

    if (more) {
      const int want = tt + 1;
      // wave-local drain of the h stores (pf loads long since returned)
      asm volatile("s_waitcnt vmcnt(0)" ::: "memory");
      if (l == 0) st_i32_llc(tgb + want * 16 + wv16, want);
      // non-critical outputs issued while others converge
      if (HoutBf) {
#pragma unroll
        for (int r = 0; r < 4; ++r)
          HoutBf[((size_t)tt * 256 + rowb + r) * 256 + jj] = f2bf(hnew[r]);
      }
      // poll all 16 wave-flags of this bgroup
      while (poll16_min(tgb + want * 16) < want)
        __builtin_amdgcn_s_sleep(1);
      const u16* hr = ((tt + 1) & 1) ? hx1 : hx0;
      ISSUE_GLDS(hr, (tt + 1) & 1);
    } else {
      if (HoutBf) {
#pragma unroll
        for (int r = 0; r < 4; ++r)
          HoutBf[((size_t)tt * 256 + rowb + r) * 256 + jj] = f2bf(hnew[r]);
      }
      if (hlast) {
#pragma unroll
        for (int r = 0; r < 4; ++r)
          hlast[(rowb + r) * kH + jj] = hnew[r];
      }
    }
  }
#undef ISSUE_GLDS

#pragma unroll
  for (int r = 0; r < 4; ++r) cstate[(rowb + r) * kH + jj] = c4[r];
}

// out[b][n] = sum_k hlast[b][k] * fcw[n][k] + fcb[n]
__global__ __launch_bounds__(128) void fc_kernel(
    const float* __restrict__ hlast, const float* __restrict__ fcw,
    const float* __restrict__ fcb, float* __restrict__ out) {
  const int b = blockIdx.x;
  const int n = threadIdx.x;
  __shared__ float sh[kH];
  sh[n] = hlast[b * kH + n];
  sh[n + 128] = hlast[b * kH + n + 128];
  __syncthreads();
  if (n < kNC) {
    float a = fcb[n];
    const float* wrow = fcw + n * kH;
#pragma unroll 8
    for (int k = 0; k < kH; ++k) a += sh[k] * wrow[k];
    out[b * kNC + n] = a;
  }
}

}  // namespace

extern "C" void kernel_launch(void* const* d_in, const int* in_sizes, int n_in,
                              void* d_out, int out_size, void* d_ws, size_t ws_size,
                              hipStream_t stream) {
  (void)in_sizes; (void)n_in; (void)out_size; (void)ws_size;
  const float* x    = (const float*)d_in[0];
  const float* Wih0 = (const float*)d_in[1];
  const float* Whh0 = (const float*)d_in[2];
  const float* bih0 = (const float*)d_in[3];
  const float* bhh0 = (const float*)d_in[4];
  const float* Wih1 = (const float*)d_in[5];
  const float* Whh1 = (const float*)d_in[6];
  const float* bih1 = (const float*)d_in[7];
  const float* bhh1 = (const float*)d_in[8];
  const float* fcw  = (const float*)d_in[9];
  const float* fcb  = (const float*)d_in[10];
  float* out = (float*)d_out;

  char* base = (char*)d_ws;
  size_t off = 0;
  auto take = [&](size_t sz) { char* p = base + off; off += (sz + 255) & ~(size_t)255; return p; };
  const size_t szP2   = (size_t)kB * kCT * kG * 2;        // 32 MB bf16
  const size_t szXbf  = (size_t)kT * kB * kIn * 2;        // 32 MB
  const size_t szH0   = (size_t)kCT * kB * kH * 2;        // 8 MB
  const size_t szC    = (size_t)kB * kH * 4;              // 256 KB
  const size_t szHx   = (size_t)2 * kB * kH * 2;          // 256 KB
  const size_t szWih0 = (size_t)64 * (kIn / 32) * 512 * 2;
  const size_t szWih1 = (size_t)64 * (kH / 32) * 512 * 2;
  const size_t szWhh  = (size_t)262144 * 2;
  const size_t szTags = (size_t)16 * 16 * 1024 * 4;       // 16 slots x 64KB
  const size_t szGd   = (size_t)8 * kGdStride * 4;        // 8 slots x 5KB

  u16* P2a0 = (u16*)take(szP2);
  u16* P2a1 = (u16*)take(szP2);
  u16* P2b  = (u16*)take(szP2);
  u16* xbf  = (u16*)take(szXbf);
  u16* H0a  = (u16*)take(szH0);
  u16* H0b  = (u16*)take(szH0);
  float* c0s = (float*)take(szC);
  float* c1s = (float*)take(szC);
  float* h1s = (float*)take(szC);
  u16* hxA = (u16*)take(szHx);
  u16* hxB = (u16*)take(szHx);
  u16* WpIh0 = (u16*)take(szWih0);
  u16* WpIh1 = (u16*)take(szWih1);
  u16* Wpk0 = (u16*)take(szWhh);
  u16* Wpk1 = (u16*)take(szWhh);
  int* tags = (int*)take(szTags);
  int* gd   = (int*)take(szGd);

  hipMemsetAsync(tags, 0, szTags, stream);
  hipMemsetAsync(gd, 0, szGd, stream);
  hipMemsetAsync(hxA, 0, szHx, stream);
  hipMemsetAsync(hxB, 0, szHx, stream);

  conv_x<<<dim3(16384), dim3(256), 0, stream>>>(x, xbf);
  pack_wih_frag<kIn><<<dim3(512), dim3(256), 0, stream>>>(Wih0, WpIh0);
  pack_wih_frag<kH><<<dim3(1024), dim3(256), 0, stream>>>(Wih1, WpIh1);
  pack_whh_frag<<<dim3(1024), dim3(256), 0, stream>>>(Whh0, Wpk0);
  pack_whh_frag<<<dim3(1024), dim3(256), 0, stream>>>(Whh1, Wpk1);

  auto tslot = [&](int s) { return tags + (size_t)s * 16 * 1024; };
  auto gslot = [&](int s) { return gd + (size_t)s * kGdStride; };
  auto p2a = [&](int ch) { return (ch & 1) ? P2a1 : P2a0; };
  auto h0p = [&](int ch) { return (ch & 1) ? H0b : H0a; };
  const size_t ckElems = (size_t)kCT * kB * kIn;

  // gemm0(0) serial; thereafter everything rides in fused dispatches.
  gemm_flat<kIn><<<dim3(1024), dim3(256), 0, stream>>>(
      xbf, WpIh0, bih0, bhh0, P2a0);

  // F(0) = rec0(0) ∥ gemm0(1)
  fused_step<<<dim3(2176), dim3(256), 0, stream>>>(
      P2a0, Wpk0, c0s, H0a, hxA, tslot(0), 1,
      nullptr, nullptr, nullptr, nullptr, nullptr, nullptr, 0, nullptr,
      nullptr, nullptr, nullptr, nullptr, nullptr,
      xbf + ckElems, P2a1, WpIh0, bih0, bhh0);

  // F(ch) = rec0(ch) ∥ rec1(ch-1) ∥ gemm1(ch-1) ∥ gemm0(ch+1)
  for (int ch = 1; ch < kNCh; ++ch) {
    const bool haveG0 = (ch + 1 < kNCh);
    fused_step<<<dim3(2176), dim3(256), 0, stream>>>(
        p2a(ch), Wpk0, c0s, h0p(ch), hxA, tslot(2 * ch), 0,
        P2b, Wpk1, c1s, h1s, hxB, tslot(2 * (ch - 1) + 1),
        (ch == 1) ? 1 : 0, gslot(ch - 1),
        h0p(ch - 1), P2b, WpIh1, bih1, bhh1,
        haveG0 ? xbf + (size_t)(ch + 1) * ckElems : nullptr,
        haveG0 ? p2a(ch + 1) : nullptr, WpIh0, bih0, bhh0);
  }

  // F(8) = rec1(7) ∥ gemm1(7)
  fused_step<<<dim3(1152), dim3(256), 0, stream>>>(
      nullptr, nullptr, nullptr, nullptr, nullptr, nullptr, 0,
      P2b, Wpk1, c1s, h1s, hxB, tslot(2 * (kNCh - 1) + 1), 0,
      gslot(kNCh - 1),
      h0p(kNCh - 1), P2b, WpIh1, bih1, bhh1,
      nullptr, nullptr, nullptr, nullptr, nullptr);

  fc_kernel<<<dim3(kB), dim3(128), 0, stream>>>(h1s, fcw, fcb, out);
}

// Round 19
// 1816.318 us; speedup vs baseline: 1.0105x; 1.0105x over previous
//
#include <hip/hip_runtime.h>
#include <math.h>

namespace {

constexpr int kB  = 256;   // batch
constexpr int kT  = 512;   // timesteps
constexpr int kIn = 128;   // layer0 input size
constexpr int kH  = 256;   // hidden
constexpr int kG  = 1024;  // 4*H
constexpr int kNC = 100;   // classes
constexpr int kCT = 64;    // timestep chunk
constexpr int kNCh = kT / kCT;

typedef __bf16 bf16x8 __attribute__((ext_vector_type(8)));
typedef float f32x4 __attribute__((ext_vector_type(4)));
typedef int i32x4 __attribute__((ext_vector_type(4)));
typedef unsigned short u16;
static_assert(sizeof(bf16x8) == 16, "bf16x8 must be 4 VGPRs");

__device__ __forceinline__ float sigm(float x) {
  return __builtin_amdgcn_rcpf(1.0f + __expf(-x));
}
__device__ __forceinline__ float tanh_f(float x) {
  const float e = __expf(-2.0f * x);
  return (1.0f - e) * __builtin_amdgcn_rcpf(1.0f + e);
}
__device__ __forceinline__ u16 f2bf(float f) {
  return __builtin_bit_cast(u16, (__bf16)f);
}
__device__ __forceinline__ float bf2f(u16 v) {
  return __builtin_bit_cast(float, ((unsigned)v) << 16);
}

// Async global->LDS, 16B/lane. aux 0 = plain (cached); 17 = sc0|sc1 (LLC).
__device__ __forceinline__ void glds16(const void* g, void* l) {
  __builtin_amdgcn_global_load_lds(
      (const __attribute__((address_space(1))) void*)g,
      (__attribute__((address_space(3))) void*)l, 16, 0, 0);
}
__device__ __forceinline__ void glds16_llc(const void* g, void* l) {
  __builtin_amdgcn_global_load_lds(
      (const __attribute__((address_space(1))) void*)g,
      (__attribute__((address_space(3))) void*)l, 16, 0, 17);
}
// Stores written through to LLC (device-visible after vmcnt drain).
__device__ __forceinline__ void st_bf16_llc(u16* p, u16 v) {
  asm volatile("global_store_short %0, %1, off sc0 sc1"
               :: "v"((unsigned long long)(uintptr_t)p), "v"(v) : "memory");
}
__device__ __forceinline__ void st_i32_llc(int* p, int v) {
  asm volatile("global_store_dword %0, %1, off sc0 sc1"
               :: "v"((unsigned long long)(uintptr_t)p), "v"(v) : "memory");
}
// Poll 16 ints (64B) at LLC scope; min of the 16. Early-clobber outputs
// (async VMEM returns must not alias the live address inputs).
__device__ __forceinline__ int poll16_min(const int* p) {
  i32x4 a, b, c, d;
  asm volatile(
      "global_load_dwordx4 %0, %4, off sc0 sc1\n\t"
      "global_load_dwordx4 %1, %5, off sc0 sc1\n\t"
      "global_load_dwordx4 %2, %6, off sc0 sc1\n\t"
      "global_load_dwordx4 %3, %7, off sc0 sc1\n\t"
      "s_waitcnt vmcnt(0)"
      : "=&v"(a), "=&v"(b), "=&v"(c), "=&v"(d)
      : "v"((unsigned long long)(uintptr_t)p),
        "v"((unsigned long long)(uintptr_t)(p + 4)),
        "v"((unsigned long long)(uintptr_t)(p + 8)),
        "v"((unsigned long long)(uintptr_t)(p + 12))
      : "memory");
  int m = a.x;
  m = min(m, a.y); m = min(m, a.z); m = min(m, a.w);
  m = min(m, b.x); m = min(m, b.y); m = min(m, b.z); m = min(m, b.w);
  m = min(m, c.x); m = min(m, c.y); m = min(m, c.z); m = min(m, c.w);
  m = min(m, d.x); m = min(m, d.y); m = min(m, d.z); m = min(m, d.w);
  return m;
}

// ---------------------------------------------------------------------------
// Pack W_hh [4H][H] fp32 -> bf16 MFMA B-frags for the recurrence:
//   flat = (((wv16*4+g)*8+kb)*64 + l)*8 + e
//   value = Whh[n][k], n = g*256 + wv16*16 + (l&15), k = kb*32 + (l>>4)*8 + e
__global__ __launch_bounds__(256) void pack_whh_frag(
    const float* __restrict__ whh, u16* __restrict__ wpk) {
  const int idx = blockIdx.x * 256 + threadIdx.x;   // 0..262143
  const int e  = idx & 7;
  const int l  = (idx >> 3) & 63;
  const int kb = (idx >> 9) & 7;
  const int g  = (idx >> 12) & 3;
  const int wv = idx >> 14;
  const int n = (g << 8) | (wv << 4) | (l & 15);
  const int k = (kb << 5) | (((l >> 4) & 3) << 3) | e;
  wpk[idx] = f2bf(whh[n * kH + k]);
}

// Pack W_ih [kG][K] fp32 -> bf16 B-frags for the projection GEMM.
template <int K>
__global__ __launch_bounds__(256) void pack_wih_frag(
    const float* __restrict__ w, u16* __restrict__ wp) {
  constexpr int kbBits = (K == 128) ? 2 : 3;
  const int idx = blockIdx.x * 256 + threadIdx.x;
  const int e  = idx & 7;
  const int l  = (idx >> 3) & 63;
  const int kb = (idx >> 9) & ((K / 32) - 1);
  const int n16 = idx >> (9 + kbBits);
  const int n = (n16 << 4) | (l & 15);
  const int k = (kb << 5) | (((l >> 4) & 3) << 3) | e;
  wp[idx] = f2bf(w[n * K + k]);
}

// x [B][T][128] fp32 -> xbf [T][B][128] bf16 (t-major for the GEMM).
__global__ __launch_bounds__(256) void conv_x(
    const float* __restrict__ x, u16* __restrict__ xbf) {
  const int f4 = blockIdx.x * 256 + threadIdx.x;   // 0..4194303
  const int rowid = f4 >> 5;                       // b*512 + t
  const int c4 = f4 & 31;
  const int b = rowid >> 9, t = rowid & 511;
  const float4 v = reinterpret_cast<const float4*>(x)[f4];
  ushort4 o;
  o.x = f2bf(v.x); o.y = f2bf(v.y); o.z = f2bf(v.z); o.w = f2bf(v.w);
  reinterpret_cast<ushort4*>(xbf)[(t * 256 + b) * 32 + c4] = o;
}

// ---------------------------------------------------------------------------
// MFMA projection GEMM body (proven round-8 structure), flat block id.
// gbid in [0,1024): g = gbid & 3, mt = gbid >> 2.
template <int K>
__device__ __forceinline__ void gemm_body(
    const u16* __restrict__ A, const u16* __restrict__ Bp,
    const float* __restrict__ b1, const float* __restrict__ b2,
    u16* __restrict__ P2, int gbid, unsigned char* smem) {
  constexpr int NKB = K / 32;
  const int g = gbid & 3, mt = gbid >> 2;
  const int tt = mt >> 2, bq = mt & 3;
  const int tid = threadIdx.x, w = tid >> 6, l = tid & 63;

  u16* albuf = (u16*)smem;                 // [2][4][512]
  u16* bbuf  = (u16*)(smem + 8192);        // [2][16][512]
  u16* sout  = (u16*)smem;                 // [4][16][256] (epilogue reuse)

  const u16* Ab = A + ((size_t)(tt * 256 + bq * 64 + w * 16 + (l & 15))) * K +
                  ((l >> 4) & 3) * 8;
  const u16* Bb = Bp + ((size_t)((g * 16 + w * 4) * NKB) * 64 + l) * 8;

  float bb[4];
#pragma unroll
  for (int j = 0; j < 4; ++j) {
    const int n = g * 256 + (w * 4 + j) * 16 + (l & 15);
    bb[j] = b1[n] + b2[n];
  }

  f32x4 acc[4][4];
#pragma unroll
  for (int mf = 0; mf < 4; ++mf)
#pragma unroll
    for (int nf = 0; nf < 4; ++nf) acc[mf][nf] = f32x4{0.f, 0.f, 0.f, 0.f};

#define STAGE(kb, buf)                                                     \
  {                                                                        \
    glds16(Ab + (kb) * 32, albuf + ((buf) * 4 + w) * 512);                 \
    _Pragma("unroll") for (int j = 0; j < 4; ++j)                          \
        glds16(Bb + ((size_t)(j * NKB + (kb)) * 64) * 8,                   \
               bbuf + ((buf) * 16 + w * 4 + j) * 512);                     \
  }

  STAGE(0, 0);
#pragma unroll
  for (int kb = 0; kb < NKB; ++kb) {
    __syncthreads();
    if (kb + 1 < NKB) STAGE(kb + 1, (kb + 1) & 1);
    const int buf = kb & 1;
    bf16x8 af[4], bf[4];
#pragma unroll
    for (int mf = 0; mf < 4; ++mf)
      af[mf] = *reinterpret_cast<const bf16x8*>(albuf + (buf * 4 + mf) * 512 + l * 8);
#pragma unroll
    for (int nf = 0; nf < 4; ++nf)
      bf[nf] = *reinterpret_cast<const bf16x8*>(bbuf + (buf * 16 + w * 4 + nf) * 512 + l * 8);
#pragma unroll
    for (int mf = 0; mf < 4; ++mf)
#pragma unroll
      for (int nf = 0; nf < 4; ++nf)
        acc[mf][nf] = __builtin_amdgcn_mfma_f32_16x16x32_bf16(
            af[mf], bf[nf], acc[mf][nf], 0, 0, 0);
  }
#undef STAGE

  __syncthreads();
#pragma unroll
  for (int mf = 0; mf < 4; ++mf)
#pragma unroll
    for (int nf = 0; nf < 4; ++nf) {
      ushort4 p;
      p.x = f2bf(acc[mf][nf][0] + bb[nf]);
      p.y = f2bf(acc[mf][nf][1] + bb[nf]);
      p.z = f2bf(acc[mf][nf][2] + bb[nf]);
      p.w = f2bf(acc[mf][nf][3] + bb[nf]);
      *reinterpret_cast<ushort4*>(
          sout + (mf * 16 + w * 4 + nf) * 256 + (l & 15) * 16 + ((l >> 4) & 3) * 4) = p;
    }
  __syncthreads();
#pragma unroll
  for (int i = 0; i < 8; ++i) {
    const int chunk = i * 8 + (tid >> 5);  // 0..63
    const int mf = chunk >> 4, wc = chunk & 15;
    const size_t dst =
        ((((size_t)(bq * 4 + mf) * 64 + tt) * 16 + wc) * 4 + g) * 256 +
        (tid & 31) * 8;
    *reinterpret_cast<uint4*>(P2 + dst) =
        *reinterpret_cast<const uint4*>(sout + (mf * 16 + wc) * 256 + (tid & 31) * 8);
  }
}

// Standalone GEMM kernel (flat 1024-block grid), for the serial launches.
template <int K>
__global__ __launch_bounds__(256, 4) void gemm_flat(
    const u16* __restrict__ A, const u16* __restrict__ Bp,
    const float* __restrict__ b1, const float* __restrict__ b2,
    u16* __restrict__ P2) {
  __shared__ __align__(16) unsigned char smem[40960];
  gemm_body<K>(A, Bp, b1, b2, P2, blockIdx.x, smem);
}

// ---------------------------------------------------------------------------
// Fused dispatch: blocks 0..127 = dual-role LSTM recurrence (R11 protocol,
// verbatim); blocks 128..1151 = projection GEMM (K=kIn) for the NEXT chunk
// (independent of the recs: reads xbf only, writes the other P2a buffer).
// GEMM blocks never wait on anything -> no placement deadlock possible.
__global__ __launch_bounds__(256, 1) void fused_step(
    const u16* __restrict__ P2_0, const u16* __restrict__ wpk_0,
    float* __restrict__ cs_0, u16* __restrict__ Ho_0, float* __restrict__ hl_0,
    u16* __restrict__ hx_0, int* __restrict__ tg_0, int first_0,
    const u16* __restrict__ P2_1, const u16* __restrict__ wpk_1,
    float* __restrict__ cs_1, u16* __restrict__ Ho_1, float* __restrict__ hl_1,
    u16* __restrict__ hx_1, int* __restrict__ tg_1, int first_1,
    const u16* __restrict__ Ag, const u16* __restrict__ Bg,
    const float* __restrict__ b1g, const float* __restrict__ b2g,
    u16* __restrict__ Pg) {
  __shared__ __align__(16) unsigned char smem[40960];

  if (blockIdx.x >= 128) {
    if (Ag) gemm_body<kIn>(Ag, Bg, b1g, b2g, Pg, blockIdx.x - 128, smem);
    return;
  }

  // ---------------- R11 recurrence, verbatim ----------------
  const int role = blockIdx.x >> 6;
  const u16* P2  = role ? P2_1 : P2_0;
  if (!P2) return;
  const u16* wpk = role ? wpk_1 : wpk_0;
  float* cstate  = role ? cs_1 : cs_0;
  u16* HoutBf    = role ? Ho_1 : Ho_0;
  float* hlast   = role ? hl_1 : hl_0;
  u16* hx        = role ? hx_1 : hx_0;
  int* tags      = role ? tg_1 : tg_0;
  const int first = role ? first_1 : first_0;

  const int bid6 = blockIdx.x & 63;
  const int tid = threadIdx.x;
  const int ug = tid >> 6;            // wave in block (0..3)
  const int l  = tid & 63;
  const int bblk = bid6 & 15;         // batch group (16 rows)
  const int hs   = bid6 >> 4;         // hidden slice (64 units)
  const int R0 = bblk << 4;
  const int wv16 = (hs << 2) | ug;
  const int jj = (wv16 << 4) | (l & 15);
  const int mg = ((l >> 4) & 3) << 2;
  const int rowb = R0 + mg;

  u16 (*albuf)[8][512] = reinterpret_cast<u16 (*)[8][512]>(smem);  // 16KB

  int* tgb = tags + bblk * 1024;      // 64 steps x 16 wave-flags
  u16* hx0 = hx;
  u16* hx1 = hx + (size_t)kB * kH;

  // resident B-frags: 4 gates x 8 kb = 128 VGPRs, pinned
  bf16x8 wr[4][8];
#pragma unroll
  for (int g = 0; g < 4; ++g)
#pragma unroll
    for (int kb = 0; kb < 8; ++kb) {
      wr[g][kb] = *reinterpret_cast<const bf16x8*>(
          wpk + (size_t)(((wv16 * 4 + g) * 8 + kb) * 64 + l) * 8);
      asm volatile("" : "+v"(wr[g][kb]));
    }

  // ---- c state ----
  f32x4 c4;
  float hnew[4];
  if (first) {
#pragma unroll
    for (int r = 0; r < 4; ++r) c4[r] = 0.f;
  } else {
#pragma unroll
    for (int r = 0; r < 4; ++r) c4[r] = cstate[(rowb + r) * kH + jj];
  }

  // P2 (bf16) lane base
  const u16* __restrict__ Pb =
      P2 + ((size_t)bblk * 64 * 16 + wv16) * 1024 + ((l & 15) << 4) + mg;
  ushort4 pf[4];
#pragma unroll
  for (int g = 0; g < 4; ++g)
    pf[g] = *reinterpret_cast<const ushort4*>(Pb + (g << 8));

  const int gkb = ug << 1;
#define ISSUE_GLDS(buf, bsel)                                               \
  {                                                                         \
    _Pragma("unroll") for (int q = 0; q < 2; ++q) {                         \
      const int kb = gkb + q;                                               \
      glds16_llc((buf) + ((size_t)(R0 + (l & 15))) * 256 + kb * 32 +        \
                     ((l >> 4) & 3) * 8,                                    \
                 &albuf[bsel][kb][0]);                                      \
    }                                                                       \
  }

  ISSUE_GLDS(hx0, 0);

  for (int tt = 0; tt < kCT; ++tt) {
    __syncthreads();  // [A] albuf[tt&1] + all waves' glds drained

    f32x4 acc[4];
#pragma unroll
    for (int g = 0; g < 4; ++g) {
      acc[g][0] = bf2f(pf[g].x);
      acc[g][1] = bf2f(pf[g].y);
      acc[g][2] = bf2f(pf[g].z);
      acc[g][3] = bf2f(pf[g].w);
    }
    if (tt + 1 < kCT) {
#pragma unroll
      for (int g = 0; g < 4; ++g)
        pf[g] = *reinterpret_cast<const ushort4*>(
            Pb + (size_t)(tt + 1) * 16384 + (g << 8));
    }

    const u16* ab = &albuf[tt & 1][0][0];
#pragma unroll
    for (int kb = 0; kb < 8; ++kb) {
      const bf16x8 a = *reinterpret_cast<const bf16x8*>(ab + kb * 512 + l * 8);
      acc[0] = __builtin_amdgcn_mfma_f32_16x16x32_bf16(a, wr[0][kb], acc[0], 0, 0, 0);
      acc[1] = __builtin_amdgcn_mfma_f32_16x16x32_bf16(a, wr[1][kb], acc[1], 0, 0, 0);
      acc[2] = __builtin_amdgcn_mfma_f32_16x16x32_bf16(a, wr[2][kb], acc[2], 0, 0, 0);
      acc[3] = __builtin_amdgcn_mfma_f32_16x16x32_bf16(a, wr[3][kb], acc[3], 0, 0, 0);
    }

#pragma unroll
    for (int r = 0; r < 4; ++r) {
      const float ig = sigm(acc[0][r]);
      const float fg = sigm(acc[1][r]);
      const float gg = tanh_f(acc[2][r]);
      const float og = sigm(acc[3][r]);
      const float cc = fg * c4[r] + ig * gg;
      c4[r] = cc;
      hnew[r] = og * tanh_f(cc);
    }

    // publish h slice (sc0sc1 -> LLC)
    u16* hw = ((tt + 1) & 1) ? hx1 : hx0;
#pragma unroll
    for (int r = 0; r < 4; ++r)
      st_bf16_llc(hw + ((size_t)(rowb + r) << 8) + jj, f2bf(hnew[r]));

    if (tt + 1 < kCT) {
      const int want = tt + 1;
      // wave-local drain of the h stores, then this wave's done-flag
      asm volatile("s_waitcnt vmcnt(0)" ::: "memory");
      if (l == 0) st_i32_llc(tgb + want * 16 + (hs * 4 + ug), want);
      // non-critical outputs issued while others converge
      if (HoutBf) {
#pragma unroll
        for (int r = 0; r < 4; ++r)
          HoutBf[((size_t)tt * 256 + rowb + r) * 256 + jj] = f2bf(hnew[r]);
      }
      // poll all 16 wave-flags of this bgroup
      while (poll16_min(tgb + want * 16) < want)
        __builtin_amdgcn_s_sleep(1);
      const u16* hr = ((tt + 1) & 1) ? hx1 : hx0;
      ISSUE_GLDS(hr, (tt + 1) & 1);
    } else {
      if (HoutBf) {
#pragma unroll
        for (int r = 0; r < 4; ++r)
          HoutBf[((size_t)tt * 256 + rowb + r) * 256 + jj] = f2bf(hnew[r]);
      }
      if (hlast) {
#pragma unroll
        for (int r = 0; r < 4; ++r)
          hlast[(rowb + r) * kH + jj] = hnew[r];
      }
    }
  }
#undef ISSUE_GLDS

#pragma unroll
  for (int r = 0; r < 4; ++r) cstate[(rowb + r) * kH + jj] = c4[r];
}

// out[b][n] = sum_k hlast[b][k] * fcw[n][k] + fcb[n]
__global__ __launch_bounds__(128) void fc_kernel(
    const float* __restrict__ hlast, const float* __restrict__ fcw,
    const float* __restrict__ fcb, float* __restrict__ out) {
  const int b = blockIdx.x;
  const int n = threadIdx.x;
  __shared__ float sh[kH];
  sh[n] = hlast[b * kH + n];
  sh[n + 128] = hlast[b * kH + n + 128];
  __syncthreads();
  if (n < kNC) {
    float a = fcb[n];
    const float* wrow = fcw + n * kH;
#pragma unroll 8
    for (int k = 0; k < kH; ++k) a += sh[k] * wrow[k];
    out[b * kNC + n] = a;
  }
}

}  // namespace

extern "C" void kernel_launch(void* const* d_in, const int* in_sizes, int n_in,
                              void* d_out, int out_size, void* d_ws, size_t ws_size,
                              hipStream_t stream) {
  (void)in_sizes; (void)n_in; (void)out_size; (void)ws_size;
  const float* x    = (const float*)d_in[0];
  const float* Wih0 = (const float*)d_in[1];
  const float* Whh0 = (const float*)d_in[2];
  const float* bih0 = (const float*)d_in[3];
  const float* bhh0 = (const float*)d_in[4];
  const float* Wih1 = (const float*)d_in[5];
  const float* Whh1 = (const float*)d_in[6];
  const float* bih1 = (const float*)d_in[7];
  const float* bhh1 = (const float*)d_in[8];
  const float* fcw  = (const float*)d_in[9];
  const float* fcb  = (const float*)d_in[10];
  float* out = (float*)d_out;

  char* base = (char*)d_ws;
  size_t off = 0;
  auto take = [&](size_t sz) { char* p = base + off; off += (sz + 255) & ~(size_t)255; return p; };
  const size_t szP2   = (size_t)kB * kCT * kG * 2;        // 32 MB bf16
  const size_t szXbf  = (size_t)kT * kB * kIn * 2;        // 32 MB
  const size_t szH0   = (size_t)kCT * kB * kH * 2;        // 8 MB
  const size_t szC    = (size_t)kB * kH * 4;              // 256 KB
  const size_t szHx   = (size_t)2 * kB * kH * 2;          // 256 KB
  const size_t szWih0 = (size_t)64 * (kIn / 32) * 512 * 2;
  const size_t szWih1 = (size_t)64 * (kH / 32) * 512 * 2;
  const size_t szWhh  = (size_t)262144 * 2;
  const size_t szTags = (size_t)16 * 16 * 1024 * 4;       // 16 slots x 64KB

  u16* P2a0 = (u16*)take(szP2);
  u16* P2a1 = (u16*)take(szP2);
  u16* P2b  = (u16*)take(szP2);
  u16* xbf  = (u16*)take(szXbf);
  u16* H0bf = (u16*)take(szH0);
  float* c0s = (float*)take(szC);
  float* c1s = (float*)take(szC);
  float* h1s = (float*)take(szC);
  u16* hxA = (u16*)take(szHx);
  u16* hxB = (u16*)take(szHx);
  u16* WpIh0 = (u16*)take(szWih0);
  u16* WpIh1 = (u16*)take(szWih1);
  u16* Wpk0 = (u16*)take(szWhh);
  u16* Wpk1 = (u16*)take(szWhh);
  int* tags = (int*)take(szTags);

  hipMemsetAsync(tags, 0, szTags, stream);
  hipMemsetAsync(hxA, 0, szHx, stream);
  hipMemsetAsync(hxB, 0, szHx, stream);

  conv_x<<<dim3(16384), dim3(256), 0, stream>>>(x, xbf);
  pack_wih_frag<kIn><<<dim3(512), dim3(256), 0, stream>>>(Wih0, WpIh0);
  pack_wih_frag<kH><<<dim3(1024), dim3(256), 0, stream>>>(Wih1, WpIh1);
  pack_whh_frag<<<dim3(1024), dim3(256), 0, stream>>>(Whh0, Wpk0);
  pack_whh_frag<<<dim3(1024), dim3(256), 0, stream>>>(Whh1, Wpk1);

  auto tslot = [&](int s) { return tags + (size_t)s * 16 * 1024; };
  auto p2a = [&](int ch) { return (ch & 1) ? P2a1 : P2a0; };
  const size_t ckElems = (size_t)kCT * kB * kIn;

  // gemm0(0) serial; thereafter gemm0(ch+1) rides inside F(ch).
  gemm_flat<kIn><<<dim3(1024), dim3(256), 0, stream>>>(
      xbf, WpIh0, bih0, bhh0, P2a0);

  // F(0) = rec0(0) ∥ gemm0(1)
  fused_step<<<dim3(1152), dim3(256), 0, stream>>>(
      P2a0, Wpk0, c0s, H0bf, nullptr, hxA, tslot(0), 1,
      nullptr, nullptr, nullptr, nullptr, nullptr, nullptr, nullptr, 0,
      xbf + ckElems, WpIh0, bih0, bhh0, P2a1);

  for (int ch = 1; ch < kNCh; ++ch) {
    // gemm1(ch-1): reads H0bf written by rec0(ch-1)
    gemm_flat<kH><<<dim3(1024), dim3(256), 0, stream>>>(
        H0bf, WpIh1, bih1, bhh1, P2b);
    const bool haveG = (ch + 1 < kNCh);
    const u16* gA = haveG ? xbf + (size_t)(ch + 1) * ckElems : nullptr;
    u16* gP = haveG ? p2a(ch + 1) : nullptr;
    const int grid = haveG ? 1152 : 128;
    // F(ch) = rec0(ch) ∥ rec1(ch-1) ∥ gemm0(ch+1)
    fused_step<<<dim3(grid), dim3(256), 0, stream>>>(
        p2a(ch), Wpk0, c0s, H0bf, nullptr, hxA, tslot(2 * ch), 0,
        P2b, Wpk1, c1s, nullptr, h1s, hxB, tslot(2 * (ch - 1) + 1),
        (ch == 1) ? 1 : 0,
        gA, WpIh0, bih0, bhh0, gP);
  }

  // tail: gemm1(7) then rec1(7)
  gemm_flat<kH><<<dim3(1024), dim3(256), 0, stream>>>(
      H0bf, WpIh1, bih1, bhh1, P2b);
  fused_step<<<dim3(128), dim3(256), 0, stream>>>(
      nullptr, nullptr, nullptr, nullptr, nullptr, nullptr, nullptr, 0,
      P2b, Wpk1, c1s, nullptr, h1s, hxB, tslot(2 * (kNCh - 1) + 1), 0,
      nullptr, nullptr, nullptr, nullptr, nullptr);
  fc_kernel<<<dim3(kB), dim3(128), 0, stream>>>(h1s, fcw, fcb, out);
}